// Round 1
// baseline (187.383 us; speedup 1.0000x reference)
//
#include <hip/hip_runtime.h>

// Cost volume, D=4: out[b,s,h,w] = mean_c feat1[b,c,h,w] * feat2[b,c,h,w+s-4]
// feat1/feat2: (8, 256, 96, 320) f32; out: (8, 9, 96, 320) f32.
// Memory-bound: ~512 MB ideal traffic -> ~85 us at 6.3 TB/s.

constexpr int B  = 8;
constexpr int C  = 256;
constexpr int H  = 96;
constexpr int W  = 320;
constexpr int NS = 9;        // 2*D+1 shifts
constexpr int QT = W / 4;    // 80 float4 per row
constexpr int RPB = 4;       // rows per block -> 320 threads
constexpr int NC = 4;        // channel chunks -> 768 blocks = 3/CU exactly
constexpr int CCH = C / NC;  // 64 channels per block
constexpr int HW = H * W;

__global__ void zero_out_kernel(float* __restrict__ out, int n) {
    int i = blockIdx.x * blockDim.x + threadIdx.x;
    int stride = gridDim.x * blockDim.x;
    for (; i < n; i += stride) out[i] = 0.0f;
}

__global__ __launch_bounds__(RPB * QT, 4)
void cost_volume_kernel(const float* __restrict__ f1,
                        const float* __restrict__ f2,
                        float* __restrict__ out) {
    const int tid = threadIdx.x;
    const int q   = tid % QT;      // float4 index within the row
    const int r   = tid / QT;      // row within block (0..3)

    const int blk    = blockIdx.x;
    const int cchunk = blk % NC;
    const int rowblk = blk / NC;               // 0 .. B*H/RPB-1
    const int hb     = rowblk % (H / RPB);
    const int b      = rowblk / (H / RPB);
    const int h      = hb * RPB + r;
    const int c0     = cchunk * CCH;

    const size_t rowoff = ((size_t)(b * C + c0) * H + h) * (size_t)W + 4 * q;
    const float* p1 = f1 + rowoff;
    const float* p2 = f2 + rowoff;

    float acc[4][NS];
#pragma unroll
    for (int j = 0; j < 4; ++j)
#pragma unroll
        for (int s = 0; s < NS; ++s) acc[j][s] = 0.0f;

    const bool has_lo = (q > 0);
    const bool has_hi = (q < QT - 1);

#pragma unroll 2
    for (int c = 0; c < CCH; ++c) {
        float4 a  = *reinterpret_cast<const float4*>(p1);
        float4 x1 = *reinterpret_cast<const float4*>(p2);
        float4 x0 = make_float4(0.f, 0.f, 0.f, 0.f);
        float4 x2 = make_float4(0.f, 0.f, 0.f, 0.f);
        if (has_lo) x0 = *reinterpret_cast<const float4*>(p2 - 4);
        if (has_hi) x2 = *reinterpret_cast<const float4*>(p2 + 4);

        // window x[0..11] = feat2 row elements (4q-4 .. 4q+7), zero outside
        float x[12] = {x0.x, x0.y, x0.z, x0.w,
                       x1.x, x1.y, x1.z, x1.w,
                       x2.x, x2.y, x2.z, x2.w};
        float av[4] = {a.x, a.y, a.z, a.w};

#pragma unroll
        for (int j = 0; j < 4; ++j)
#pragma unroll
            for (int s = 0; s < NS; ++s)
                acc[j][s] = fmaf(av[j], x[j + s], acc[j][s]);

        p1 += HW;
        p2 += HW;
    }

    const float scale = 1.0f / (float)C;
#pragma unroll
    for (int s = 0; s < NS; ++s) {
        float* orow = out + ((size_t)(b * NS + s) * H + h) * (size_t)W + 4 * q;
#pragma unroll
        for (int j = 0; j < 4; ++j)
            atomicAdd(orow + j, acc[j][s] * scale);
    }
}

extern "C" void kernel_launch(void* const* d_in, const int* in_sizes, int n_in,
                              void* d_out, int out_size, void* d_ws, size_t ws_size,
                              hipStream_t stream) {
    const float* f1 = (const float*)d_in[0];
    const float* f2 = (const float*)d_in[1];
    float* out = (float*)d_out;

    // Zero the output (harness poisons it 0xAA; atomics accumulate into it).
    hipLaunchKernelGGL(zero_out_kernel, dim3(512), dim3(256), 0, stream,
                       out, out_size);

    dim3 grid(B * (H / RPB) * NC);   // 8 * 24 * 4 = 768 blocks, 3/CU
    dim3 block(RPB * QT);            // 320 threads
    hipLaunchKernelGGL(cost_volume_kernel, grid, block, 0, stream, f1, f2, out);
}

// Round 2
// 121.194 us; speedup vs baseline: 1.5461x; 1.5461x over previous
//
#include <hip/hip_runtime.h>

// Cost volume, D=4: out[b,s,h,w] = mean_c feat1[b,c,h,w] * feat2[b,c,h,w+s-4]
// feat1/feat2: (8, 256, 96, 320) f32; out: (8, 9, 96, 320) f32.
// Memory-bound: ~580 MB total traffic (inputs + ws partials) -> ~95 us at 6.3 TB/s.

constexpr int B  = 8;
constexpr int C  = 256;
constexpr int H  = 96;
constexpr int W  = 320;
constexpr int NS = 9;          // 2*D+1 shifts
constexpr int QT = W / 4;      // 80 float4 per row
constexpr int RPB = 4;         // rows per block -> 320 threads
constexpr int NC = 4;          // channel chunks -> 768 blocks, 15 waves/CU
constexpr int CCH = C / NC;    // 64 channels per chunk
constexpr int HW = H * W;
constexpr int OUT_ELEMS = B * NS * H * W;   // 2,211,840

__global__ void zero_out_kernel(float* __restrict__ out, int n) {
    int i = blockIdx.x * blockDim.x + threadIdx.x;
    int stride = gridDim.x * blockDim.x;
    for (; i < n; i += stride) out[i] = 0.0f;
}

// ATOMIC=false: write partial sums (one chunk's 64-channel sum) to dst, laid out
//   dst[chunk][b][s][h][w]; combined by reduce_kernel.
// ATOMIC=true : fallback if ws too small — atomicAdd scaled partials into d_out.
template <bool ATOMIC>
__global__ __launch_bounds__(RPB * QT, 4)
void cv_kernel(const float* __restrict__ f1,
               const float* __restrict__ f2,
               float* __restrict__ dst) {
    const int tid = threadIdx.x;
    const int q   = tid % QT;
    const int r   = tid / QT;

    const int blk    = blockIdx.x;
    const int cchunk = blk % NC;
    const int rowblk = blk / NC;
    const int hb     = rowblk % (H / RPB);
    const int b      = rowblk / (H / RPB);
    const int h      = hb * RPB + r;
    const int c0     = cchunk * CCH;

    const size_t off = ((size_t)(b * C + c0) * H + h) * (size_t)W + 4 * q;
    const float* p1 = f1 + off;
    const float* p2 = f2 + off;

    // Boundary handling: clamped (always-valid) addresses, zeroed on USE via
    // cndmask — keeps all loads unconditional so the compiler can pipeline.
    const bool has_lo = (q > 0);
    const bool has_hi = (q < QT - 1);
    const int  lo = has_lo ? -4 : 0;
    const int  hi = has_hi ?  4 : 0;

    float acc[4][NS];
#pragma unroll
    for (int j = 0; j < 4; ++j)
#pragma unroll
        for (int s = 0; s < NS; ++s) acc[j][s] = 0.0f;

    auto do_fma = [&](const float4& a, const float4& x0,
                      const float4& x1, const float4& x2) {
        float x[12] = {has_lo ? x0.x : 0.f, has_lo ? x0.y : 0.f,
                       has_lo ? x0.z : 0.f, has_lo ? x0.w : 0.f,
                       x1.x, x1.y, x1.z, x1.w,
                       has_hi ? x2.x : 0.f, has_hi ? x2.y : 0.f,
                       has_hi ? x2.z : 0.f, has_hi ? x2.w : 0.f};
        float av[4] = {a.x, a.y, a.z, a.w};
#pragma unroll
        for (int j = 0; j < 4; ++j)
#pragma unroll
            for (int s = 0; s < NS; ++s)
                acc[j][s] = fmaf(av[j], x[j + s], acc[j][s]);
    };

    // Depth-2 software pipeline: iteration c+1's loads issue before c's FMAs.
    float4 a  = *reinterpret_cast<const float4*>(p1);
    float4 x0 = *reinterpret_cast<const float4*>(p2 + lo);
    float4 x1 = *reinterpret_cast<const float4*>(p2);
    float4 x2 = *reinterpret_cast<const float4*>(p2 + hi);

#pragma unroll 2
    for (int c = 0; c < CCH - 1; ++c) {
        p1 += HW;
        p2 += HW;
        float4 an  = *reinterpret_cast<const float4*>(p1);
        float4 x0n = *reinterpret_cast<const float4*>(p2 + lo);
        float4 x1n = *reinterpret_cast<const float4*>(p2);
        float4 x2n = *reinterpret_cast<const float4*>(p2 + hi);
        do_fma(a, x0, x1, x2);
        a = an; x0 = x0n; x1 = x1n; x2 = x2n;
    }
    do_fma(a, x0, x1, x2);

    if (ATOMIC) {
        const float scale = 1.0f / (float)C;
#pragma unroll
        for (int s = 0; s < NS; ++s) {
            float* orow = dst + ((size_t)(b * NS + s) * H + h) * (size_t)W + 4 * q;
#pragma unroll
            for (int j = 0; j < 4; ++j)
                atomicAdd(orow + j, acc[j][s] * scale);
        }
    } else {
        float* base = dst + (size_t)cchunk * OUT_ELEMS;
#pragma unroll
        for (int s = 0; s < NS; ++s) {
            float4 v = make_float4(acc[0][s], acc[1][s], acc[2][s], acc[3][s]);
            float* orow = base + ((size_t)(b * NS + s) * H + h) * (size_t)W + 4 * q;
            *reinterpret_cast<float4*>(orow) = v;
        }
    }
}

__global__ void reduce_kernel(const float* __restrict__ part,
                              float* __restrict__ out, int n4) {
    const float scale = 1.0f / (float)C;
    const float4* p = reinterpret_cast<const float4*>(part);
    float4* o = reinterpret_cast<float4*>(out);
    int i = blockIdx.x * blockDim.x + threadIdx.x;
    int stride = gridDim.x * blockDim.x;
    const int n4e = OUT_ELEMS / 4;
    for (; i < n4; i += stride) {
        float4 v0 = p[i];
        float4 v1 = p[i + n4e];
        float4 v2 = p[i + 2 * n4e];
        float4 v3 = p[i + 3 * n4e];
        float4 r;
        r.x = (v0.x + v1.x + v2.x + v3.x) * scale;
        r.y = (v0.y + v1.y + v2.y + v3.y) * scale;
        r.z = (v0.z + v1.z + v2.z + v3.z) * scale;
        r.w = (v0.w + v1.w + v2.w + v3.w) * scale;
        o[i] = r;
    }
}

extern "C" void kernel_launch(void* const* d_in, const int* in_sizes, int n_in,
                              void* d_out, int out_size, void* d_ws, size_t ws_size,
                              hipStream_t stream) {
    const float* f1 = (const float*)d_in[0];
    const float* f2 = (const float*)d_in[1];
    float* out = (float*)d_out;

    dim3 grid(B * (H / RPB) * NC);   // 768 blocks
    dim3 block(RPB * QT);            // 320 threads

    const size_t need = (size_t)NC * OUT_ELEMS * sizeof(float);  // 35.4 MB
    if (ws_size >= need) {
        float* part = (float*)d_ws;
        hipLaunchKernelGGL((cv_kernel<false>), grid, block, 0, stream, f1, f2, part);
        const int n4 = OUT_ELEMS / 4;
        hipLaunchKernelGGL(reduce_kernel, dim3(2048), dim3(256), 0, stream,
                           part, out, n4);
    } else {
        hipLaunchKernelGGL(zero_out_kernel, dim3(512), dim3(256), 0, stream,
                           out, out_size);
        hipLaunchKernelGGL((cv_kernel<true>), grid, block, 0, stream, f1, f2, out);
    }
}